// Round 2
// baseline (866.003 us; speedup 1.0000x reference)
//
#include <hip/hip_runtime.h>
#include <hip/hip_bf16.h>

typedef __attribute__((ext_vector_type(8))) short short8;
typedef __attribute__((ext_vector_type(4))) float f32x4;
typedef __attribute__((ext_vector_type(4))) int   int4v;

__device__ __forceinline__ short f2bf(float f) {
  unsigned u = __float_as_uint(f);
  u += 0x7fffu + ((u >> 16) & 1u);   // RNE
  return (short)(u >> 16);
}

__device__ __forceinline__ void gload16(const short* g, short* l) {
  __builtin_amdgcn_global_load_lds(
      (const __attribute__((address_space(1))) unsigned int*)g,
      (__attribute__((address_space(3))) unsigned int*)l, 16, 0, 0);
}

// ---------------- L2 norm scale: scale[n*P+p] = 1/(||feat0[n,:,p]|| + 1e-10) ----------
__global__ __launch_bounds__(256) void l2norm_kernel(const float* __restrict__ f0,
                                                     float* __restrict__ scale,
                                                     int C, int P, int total) {
  __shared__ float red[4][64];
  int pl = threadIdx.x & 63;
  int cg = threadIdx.x >> 6;
  int pos = blockIdx.x * 64 + pl;
  float s = 0.f;
  if (pos < total) {
    int n = pos / P, sp = pos - n * P;
    const float* base = f0 + (size_t)n * C * P + sp;
    int c0 = cg * (C >> 2), c1 = c0 + (C >> 2);
    for (int c = c0; c < c1; ++c) {
      float v = base[(size_t)c * P];
      s += v * v;
    }
  }
  red[cg][pl] = s;
  __syncthreads();
  if (threadIdx.x < 64 && pos < total) {
    float tot = red[0][pl] + red[1][pl] + red[2][pl] + red[3][pl];
    scale[pos] = 1.0f / (sqrtf(tot) + 1e-10f);
  }
}

// ------------- NCHW fp32 -> padded NHWC bf16 (optional per-pos scale, per-ch wt) ------
__global__ __launch_bounds__(256) void to_nhwc_kernel(const float* __restrict__ src,
    short* __restrict__ dst, const float* __restrict__ rowscale,
    const float* __restrict__ chw, int C, int H, int W, int Wp, int nstride, int hh) {
  __shared__ float tile[32][33];
  int n = blockIdx.z;
  int P = H * W;
  int p0 = blockIdx.x * 32, c0 = blockIdx.y * 32;
  int tp = threadIdx.x & 31, tr = threadIdx.x >> 5;
  const float* s = src + (size_t)n * C * P;
  #pragma unroll
  for (int i = 0; i < 4; ++i) {
    int cl = tr + i * 8;
    int p = p0 + tp;
    tile[cl][tp] = (p < P) ? s[(size_t)(c0 + cl) * P + p] : 0.f;
  }
  __syncthreads();
  #pragma unroll
  for (int i = 0; i < 4; ++i) {
    int pl = tr + i * 8;
    int p = p0 + pl;
    if (p >= P) continue;
    int c = c0 + tp;
    float v = tile[tp][pl];
    if (chw)      v *= chw[c];
    if (rowscale) v *= rowscale[n * P + p];
    int y = p / W, x = p - y * W;
    dst[((size_t)n * nstride + (y + hh) * Wp + (x + hh)) * C + c] = f2bf(v);
  }
}

// ---------------- weight repack: (Co,Ci,S) fp32 -> [co][s][ci] bf16 -------------------
struct WSeg { const float* src; short* dst; int Ci; int S; int elems; };
struct WPrep { WSeg seg[20]; };

__global__ __launch_bounds__(256) void wprep_kernel(WPrep p, int total) {
  int i = blockIdx.x * 256 + threadIdx.x;
  if (i >= total) return;
  int local = i;
  int si = 0;
  while (local >= p.seg[si].elems) { local -= p.seg[si].elems; ++si; }
  WSeg sg = p.seg[si];
  int ci = local % sg.Ci;
  int q  = local / sg.Ci;
  int s  = q % sg.S;
  int co = q / sg.S;
  float v = sg.src[((size_t)co * sg.Ci + ci) * sg.S + s];
  sg.dst[local] = f2bf(v);
}

// ---------------- conv params (padded layouts, no masks) -----------------------------
struct ConvP {
  const short* in;   // bf16 padded NHWC [16][iHp][iWp][Ci]
  const short* w;    // bf16 [Co][S][Ci]
  const float* b1;   // bias (extra) / cls bias (head)
  const float* b2;   // box bias (head)
  short* out_bf;     // extra: padded bf16 NHWC out
  float* out_f;      // head: packed d_out
  int M, Ci, iHp, iWp, Ho, Wo, Co;
  int S, kdim, stride, ioff;      // ioff = input_halo - pad (>=0)
  int oWp, onstride, oh;          // extras output padded layout
  int mbox, row_base;
};

// ---------------- 128x128 tile, global_load_lds staging (m97 structure) --------------
template<bool HEAD>
__global__ __launch_bounds__(256) void conv_gemm128(ConvP p) {
  __shared__ short As[128 * 32];
  __shared__ short Bs[128 * 32];
  int t = threadIdx.x;
  int lane = t & 63, wave = t >> 6;
  int HW = p.Ho * p.Wo;
  int instride = p.iHp * p.iWp;

  // staging: thread t covers rows (t>>2) and 64+(t>>2), k-slot (t&3)*8
  int sr = t >> 2, slot = (t & 3) * 8;
  const short* aRow[2];
  const short* bRow[2];
  #pragma unroll
  for (int i = 0; i < 2; ++i) {
    int r = sr + i * 64;
    int pos = blockIdx.x * 128 + r; if (pos >= p.M) pos = p.M - 1;
    int n = pos / HW, rem = pos - n * HW;
    int yo = rem / p.Wo, xo = rem - yo * p.Wo;
    aRow[i] = p.in + ((size_t)(n * p.iHp + yo * p.stride + p.ioff) * p.iWp
                      + xo * p.stride + p.ioff) * p.Ci + slot;
    int co = blockIdx.y * 128 + r; if (co >= p.Co) co = p.Co - 1;
    bRow[i] = p.w + (size_t)co * p.S * p.Ci + slot;
  }
  short* aDst = &As[t * 8];
  short* bDst = &Bs[t * 8];

  f32x4 acc[4][4];
  #pragma unroll
  for (int i = 0; i < 4; ++i)
    #pragma unroll
    for (int j = 0; j < 4; ++j)
      acc[i][j] = (f32x4){0.f, 0.f, 0.f, 0.f};

  int wr = (wave >> 1) * 64, wc = (wave & 1) * 64;
  int lrow = lane & 15, lk = (lane >> 4) * 8;
  const short* aRd = &As[(wr + lrow) * 32 + lk];
  const short* bRd = &Bs[(wc + lrow) * 32 + lk];

  for (int s = 0; s < p.S; ++s) {
    int dy = s / p.kdim, dx = s - dy * p.kdim;
    int toff = (dy * p.iWp + dx) * p.Ci;
    const short* a0 = aRow[0] + toff;
    const short* a1 = aRow[1] + toff;
    const short* b0p = bRow[0] + s * p.Ci;
    const short* b1p = bRow[1] + s * p.Ci;
    for (int c0 = 0; c0 < p.Ci; c0 += 32) {
      __syncthreads();                       // prior ds_reads done before overwrite
      gload16(a0 + c0, aDst);
      gload16(a1 + c0, aDst + 2048);
      gload16(b0p + c0, bDst);
      gload16(b1p + c0, bDst + 2048);
      __syncthreads();                       // loads landed (vmcnt drained at barrier)
      short8 a[4], b[4];
      #pragma unroll
      for (int i = 0; i < 4; ++i) a[i] = *reinterpret_cast<const short8*>(aRd + i * 512);
      #pragma unroll
      for (int j = 0; j < 4; ++j) b[j] = *reinterpret_cast<const short8*>(bRd + j * 512);
      #pragma unroll
      for (int i = 0; i < 4; ++i)
        #pragma unroll
        for (int j = 0; j < 4; ++j)
          acc[i][j] = __builtin_amdgcn_mfma_f32_16x16x32_bf16(a[i], b[j], acc[i][j], 0, 0, 0);
    }
  }

  int mk = p.mbox * 81;
  int r_base = (lane >> 4) * 4, c_l = lane & 15;
  #pragma unroll
  for (int i = 0; i < 4; ++i)
    #pragma unroll
    for (int j = 0; j < 4; ++j)
      #pragma unroll
      for (int q = 0; q < 4; ++q) {
        int po = blockIdx.x * 128 + wr + i * 16 + r_base + q;
        int co = blockIdx.y * 128 + wc + j * 16 + c_l;
        if (po >= p.M || co >= p.Co) continue;
        float v = acc[i][j][q];
        if (!HEAD) {
          int n2 = po / HW, sp = po - n2 * HW;
          int y = sp / p.Wo, x = sp - y * p.Wo;
          float v2 = fmaxf(v + p.b1[co], 0.f);
          p.out_bf[((size_t)n2 * p.onstride + (y + p.oh) * p.oWp + (x + p.oh)) * p.Co + co] = f2bf(v2);
        } else {
          int n2 = po / HW, sp = po - n2 * HW;
          int mi, col; float bias;
          if (co < mk) { mi = co / 81; col = co - mi * 81; bias = p.b1[co]; }
          else { int cbx = co - mk; mi = cbx >> 2; col = 81 + (cbx & 3); bias = p.b2[cbx]; }
          size_t orow = (size_t)n2 * 8732 + p.row_base + (size_t)sp * p.mbox + mi;
          p.out_f[orow * 85 + col] = v + bias;
        }
      }
}

// ---------------- 64x64 tile (small convs) -------------------------------------------
template<bool HEAD>
__global__ __launch_bounds__(256) void conv_gemm64(ConvP p) {
  __shared__ short As[64 * 40];
  __shared__ short Bs[64 * 40];
  int t = threadIdx.x;
  int srow = t >> 2;
  int skc  = (t & 3) << 3;
  int HW = p.Ho * p.Wo;
  int pos = blockIdx.x * 64 + srow; if (pos >= p.M) pos = p.M - 1;
  int n = pos / HW, rem = pos - n * HW;
  int yo = rem / p.Wo, xo = rem - yo * p.Wo;
  int co_s = blockIdx.y * 64 + srow; if (co_s >= p.Co) co_s = p.Co - 1;
  const short* wrow  = p.w + (size_t)co_s * p.S * p.Ci + skc;
  const short* abase = p.in + ((size_t)(n * p.iHp + yo * p.stride + p.ioff) * p.iWp
                               + xo * p.stride + p.ioff) * p.Ci + skc;

  f32x4 acc[2][2];
  #pragma unroll
  for (int i = 0; i < 2; ++i)
    #pragma unroll
    for (int j = 0; j < 2; ++j)
      acc[i][j] = (f32x4){0.f, 0.f, 0.f, 0.f};

  int lane = t & 63, wave = t >> 6;
  int wr = (wave >> 1) * 32, wc = (wave & 1) * 32;
  int lrow = lane & 15;
  int lk = (lane >> 4) << 3;
  const short* a_lds = &As[(wr + lrow) * 40 + lk];
  const short* b_lds = &Bs[(wc + lrow) * 40 + lk];

  for (int s = 0; s < p.S; ++s) {
    int dy = s / p.kdim, dx = s - dy * p.kdim;
    const short* arow = abase + (dy * p.iWp + dx) * p.Ci;
    const short* wsub = wrow + s * p.Ci;
    for (int c0 = 0; c0 < p.Ci; c0 += 32) {
      __syncthreads();
      int4v av = *reinterpret_cast<const int4v*>(arow + c0);
      int4v bv = *reinterpret_cast<const int4v*>(wsub + c0);
      *reinterpret_cast<int4v*>(&As[srow * 40 + skc]) = av;
      *reinterpret_cast<int4v*>(&Bs[srow * 40 + skc]) = bv;
      __syncthreads();
      short8 a0 = *reinterpret_cast<const short8*>(a_lds);
      short8 a1 = *reinterpret_cast<const short8*>(a_lds + 16 * 40);
      short8 b0 = *reinterpret_cast<const short8*>(b_lds);
      short8 b1 = *reinterpret_cast<const short8*>(b_lds + 16 * 40);
      acc[0][0] = __builtin_amdgcn_mfma_f32_16x16x32_bf16(a0, b0, acc[0][0], 0, 0, 0);
      acc[0][1] = __builtin_amdgcn_mfma_f32_16x16x32_bf16(a0, b1, acc[0][1], 0, 0, 0);
      acc[1][0] = __builtin_amdgcn_mfma_f32_16x16x32_bf16(a1, b0, acc[1][0], 0, 0, 0);
      acc[1][1] = __builtin_amdgcn_mfma_f32_16x16x32_bf16(a1, b1, acc[1][1], 0, 0, 0);
    }
  }

  int mk = p.mbox * 81;
  #pragma unroll
  for (int i = 0; i < 2; ++i)
    #pragma unroll
    for (int j = 0; j < 2; ++j)
      #pragma unroll
      for (int q = 0; q < 4; ++q) {
        int po = blockIdx.x * 64 + wr + i * 16 + ((lane >> 4) << 2) + q;
        int co = blockIdx.y * 64 + wc + j * 16 + (lane & 15);
        if (po >= p.M || co >= p.Co) continue;
        float v = acc[i][j][q];
        if (!HEAD) {
          int n2 = po / HW, sp = po - n2 * HW;
          int y = sp / p.Wo, x = sp - y * p.Wo;
          float v2 = fmaxf(v + p.b1[co], 0.f);
          p.out_bf[((size_t)n2 * p.onstride + (y + p.oh) * p.oWp + (x + p.oh)) * p.Co + co] = f2bf(v2);
        } else {
          int n2 = po / HW, sp = po - n2 * HW;
          int mi, col; float bias;
          if (co < mk) { mi = co / 81; col = co - mi * 81; bias = p.b1[co]; }
          else { int cbx = co - mk; mi = cbx >> 2; col = 81 + (cbx & 3); bias = p.b2[cbx]; }
          size_t orow = (size_t)n2 * 8732 + p.row_base + (size_t)sp * p.mbox + mi;
          p.out_f[orow * 85 + col] = v + bias;
        }
      }
}

extern "C" void kernel_launch(void* const* d_in, const int* in_sizes, int n_in,
                              void* d_out, int out_size, void* d_ws, size_t ws_size,
                              hipStream_t stream) {
  const float* feat0 = (const float*)d_in[0];
  const float* feat1 = (const float*)d_in[1];
  const float* l2w   = (const float*)d_in[2];
  const float* ew[8]; const float* eb[8];
  for (int i = 0; i < 8; ++i) { ew[i] = (const float*)d_in[3 + 2 * i]; eb[i] = (const float*)d_in[4 + 2 * i]; }
  const float* cw[6]; const float* cb[6]; const float* bw[6]; const float* bb[6];
  for (int i = 0; i < 6; ++i) {
    cw[i] = (const float*)d_in[19 + 4 * i]; cb[i] = (const float*)d_in[20 + 4 * i];
    bw[i] = (const float*)d_in[21 + 4 * i]; bb[i] = (const float*)d_in[22 + 4 * i];
  }
  float* out = (float*)d_out;
  char* ws = (char*)d_ws;
  size_t off = 0;
  auto alloc = [&](size_t bytes) -> char* {
    char* p = ws + off;
    off = (off + bytes + 255) & ~(size_t)255;
    return p;
  };
  float* scale0 = (float*)alloc(23104 * 4);
  char* featStart = ws + off;
  // padded feature buffers: [16][Hp][Wp][C] bf16, halo in comments
  short* f0b = (short*)alloc((size_t)16 * 40 * 40 * 512 * 2);   // 38x38, h=1
  short* f1b = (short*)alloc((size_t)16 * 21 * 21 * 1024 * 2);  // 19x19, h=1
  short* xe0 = (short*)alloc((size_t)16 * 21 * 21 * 256 * 2);   // 19x19, h=1
  short* f2b = (short*)alloc((size_t)16 * 12 * 12 * 512 * 2);   // 10x10, h=1
  short* xe2 = (short*)alloc((size_t)16 * 12 * 12 * 128 * 2);   // 10x10, h=1
  short* f3b = (short*)alloc((size_t)16 * 7 * 7 * 256 * 2);     // 5x5,  h=1
  short* xe4 = (short*)alloc((size_t)16 * 5 * 5 * 128 * 2);     // 5x5,  h=0
  short* f4b = (short*)alloc((size_t)16 * 5 * 5 * 256 * 2);     // 3x3,  h=1
  short* xe6 = (short*)alloc((size_t)16 * 3 * 3 * 128 * 2);     // 3x3,  h=0
  short* f5b = (short*)alloc((size_t)16 * 3 * 3 * 256 * 2);     // 1x1,  h=1
  size_t featBytes = (size_t)((ws + off) - featStart);

  static const int eCo[8] = {256, 512, 128, 256, 128, 256, 128, 256};
  static const int eCi[8] = {1024, 256, 512, 128, 256, 128, 256, 128};
  static const int eS[8]  = {1, 9, 1, 9, 1, 9, 1, 9};
  static const int mbox[6] = {4, 6, 6, 6, 4, 4};
  static const int hCi[6] = {512, 1024, 512, 256, 256, 256};

  WPrep wp; int total = 0; int segi = 0;
  short* ewb[8]; short* hwb[6];
  for (int i = 0; i < 8; ++i) {
    int e = eCo[i] * eCi[i] * eS[i];
    ewb[i] = (short*)alloc((size_t)e * 2);
    wp.seg[segi++] = {ew[i], ewb[i], eCi[i], eS[i], e};
    total += e;
  }
  for (int L = 0; L < 6; ++L) {
    int co = mbox[L] * 85;
    int e = co * hCi[L] * 9;
    hwb[L] = (short*)alloc((size_t)e * 2);
    int ecls = mbox[L] * 81 * hCi[L] * 9;
    wp.seg[segi++] = {cw[L], hwb[L], hCi[L], 9, ecls};
    wp.seg[segi++] = {bw[L], hwb[L] + (size_t)mbox[L] * 81 * 9 * hCi[L], hCi[L], 9, e - ecls};
    total += e;
  }

  hipMemsetAsync(featStart, 0, featBytes, stream);
  l2norm_kernel<<<dim3((23104 + 63) / 64), 256, 0, stream>>>(feat0, scale0, 512, 1444, 23104);
  to_nhwc_kernel<<<dim3(46, 16, 16), 256, 0, stream>>>(feat0, f0b, scale0, l2w, 512, 38, 38, 40, 1600, 1);
  to_nhwc_kernel<<<dim3(12, 32, 16), 256, 0, stream>>>(feat1, f1b, nullptr, nullptr, 1024, 19, 19, 21, 441, 1);
  wprep_kernel<<<dim3((total + 255) / 256), 256, 0, stream>>>(wp, total);

  auto mkP = [&](const short* in, const short* wbuf, const float* b1, const float* b2,
                 short* outb, float* outf, int Ci, int iHp, int iWp, int Ho, int Wo,
                 int Co, int S, int kd, int st, int ioff, int oWp, int onstride, int oh,
                 int m, int rb) {
    ConvP p{}; p.in = in; p.w = wbuf; p.b1 = b1; p.b2 = b2; p.out_bf = outb; p.out_f = outf;
    p.M = 16 * Ho * Wo; p.Ci = Ci; p.iHp = iHp; p.iWp = iWp; p.Ho = Ho; p.Wo = Wo; p.Co = Co;
    p.S = S; p.kdim = kd; p.stride = st; p.ioff = ioff;
    p.oWp = oWp; p.onstride = onstride; p.oh = oh; p.mbox = m; p.row_base = rb;
    return p;
  };
  auto run128e = [&](ConvP p) {
    conv_gemm128<false><<<dim3((p.M + 127) / 128, (p.Co + 127) / 128), 256, 0, stream>>>(p);
  };
  auto run64e = [&](ConvP p) {
    conv_gemm64<false><<<dim3((p.M + 63) / 64, (p.Co + 63) / 64), 256, 0, stream>>>(p);
  };
  auto run128h = [&](ConvP p) {
    conv_gemm128<true><<<dim3((p.M + 127) / 128, (p.Co + 127) / 128), 256, 0, stream>>>(p);
  };
  auto run64h = [&](ConvP p) {
    conv_gemm64<true><<<dim3((p.M + 63) / 64, (p.Co + 63) / 64), 256, 0, stream>>>(p);
  };

  // extras chain
  run128e(mkP(f1b, ewb[0], eb[0], nullptr, xe0, nullptr, 1024, 21, 21, 19, 19, 256, 1, 1, 1, 1, 21, 441, 1, 0, 0));
  run128e(mkP(xe0, ewb[1], eb[1], nullptr, f2b, nullptr,  256, 21, 21, 10, 10, 512, 9, 3, 2, 0, 12, 144, 1, 0, 0));
  run64e (mkP(f2b, ewb[2], eb[2], nullptr, xe2, nullptr,  512, 12, 12, 10, 10, 128, 1, 1, 1, 1, 12, 144, 1, 0, 0));
  run64e (mkP(xe2, ewb[3], eb[3], nullptr, f3b, nullptr,  128, 12, 12,  5,  5, 256, 9, 3, 2, 0,  7,  49, 1, 0, 0));
  run64e (mkP(f3b, ewb[4], eb[4], nullptr, xe4, nullptr,  256,  7,  7,  5,  5, 128, 1, 1, 1, 1,  5,  25, 0, 0, 0));
  run64e (mkP(xe4, ewb[5], eb[5], nullptr, f4b, nullptr,  128,  5,  5,  3,  3, 256, 9, 3, 1, 0,  5,  25, 1, 0, 0));
  run64e (mkP(f4b, ewb[6], eb[6], nullptr, xe6, nullptr,  256,  5,  5,  3,  3, 128, 1, 1, 1, 1,  3,   9, 0, 0, 0));
  run64e (mkP(xe6, ewb[7], eb[7], nullptr, f5b, nullptr,  128,  3,  3,  1,  1, 256, 9, 3, 1, 0,  3,   9, 1, 0, 0));

  // heads (S=9, k=3, stride=1, ioff=0 since halo==pad==1)
  run128h(mkP(f0b, hwb[0], cb[0], bb[0], nullptr, out,  512, 40, 40, 38, 38, 4 * 85, 9, 3, 1, 0, 0, 0, 0, 4, 0));
  run128h(mkP(f1b, hwb[1], cb[1], bb[1], nullptr, out, 1024, 21, 21, 19, 19, 6 * 85, 9, 3, 1, 0, 0, 0, 0, 6, 5776));
  run128h(mkP(f2b, hwb[2], cb[2], bb[2], nullptr, out,  512, 12, 12, 10, 10, 6 * 85, 9, 3, 1, 0, 0, 0, 0, 6, 7942));
  run64h (mkP(f3b, hwb[3], cb[3], bb[3], nullptr, out,  256,  7,  7,  5,  5, 6 * 85, 9, 3, 1, 0, 0, 0, 0, 6, 8542));
  run64h (mkP(f4b, hwb[4], cb[4], bb[4], nullptr, out,  256,  5,  5,  3,  3, 4 * 85, 9, 3, 1, 0, 0, 0, 0, 4, 8692));
  run64h (mkP(f5b, hwb[5], cb[5], bb[5], nullptr, out,  256,  3,  3,  1,  1, 4 * 85, 9, 3, 1, 0, 0, 0, 0, 4, 8728));
}

// Round 3
// 543.116 us; speedup vs baseline: 1.5945x; 1.5945x over previous
//
#include <hip/hip_runtime.h>
#include <hip/hip_bf16.h>

typedef __attribute__((ext_vector_type(8))) short short8;
typedef __attribute__((ext_vector_type(4))) float f32x4;

__device__ __forceinline__ short f2bf(float f) {
  unsigned u = __float_as_uint(f);
  u += 0x7fffu + ((u >> 16) & 1u);   // RNE
  return (short)(u >> 16);
}

__device__ __forceinline__ void gload16(const short* g, short* l) {
  __builtin_amdgcn_global_load_lds(
      (const __attribute__((address_space(1))) unsigned int*)g,
      (__attribute__((address_space(3))) unsigned int*)l, 16, 0, 0);
}

// ---------------- L2 norm scale ------------------------------------------------------
__global__ __launch_bounds__(256) void l2norm_kernel(const float* __restrict__ f0,
                                                     float* __restrict__ scale,
                                                     int C, int P, int total) {
  __shared__ float red[4][64];
  int pl = threadIdx.x & 63;
  int cg = threadIdx.x >> 6;
  int pos = blockIdx.x * 64 + pl;
  float s = 0.f;
  if (pos < total) {
    int n = pos / P, sp = pos - n * P;
    const float* base = f0 + (size_t)n * C * P + sp;
    int c0 = cg * (C >> 2), c1 = c0 + (C >> 2);
    for (int c = c0; c < c1; ++c) {
      float v = base[(size_t)c * P];
      s += v * v;
    }
  }
  red[cg][pl] = s;
  __syncthreads();
  if (threadIdx.x < 64 && pos < total) {
    float tot = red[0][pl] + red[1][pl] + red[2][pl] + red[3][pl];
    scale[pos] = 1.0f / (sqrtf(tot) + 1e-10f);
  }
}

// ------------- NCHW fp32 -> padded NHWC bf16 -----------------------------------------
__global__ __launch_bounds__(256) void to_nhwc_kernel(const float* __restrict__ src,
    short* __restrict__ dst, const float* __restrict__ rowscale,
    const float* __restrict__ chw, int C, int H, int W, int Wp, int nstride, int hh) {
  __shared__ float tile[32][33];
  int n = blockIdx.z;
  int P = H * W;
  int p0 = blockIdx.x * 32, c0 = blockIdx.y * 32;
  int tp = threadIdx.x & 31, tr = threadIdx.x >> 5;
  const float* s = src + (size_t)n * C * P;
  #pragma unroll
  for (int i = 0; i < 4; ++i) {
    int cl = tr + i * 8;
    int p = p0 + tp;
    tile[cl][tp] = (p < P) ? s[(size_t)(c0 + cl) * P + p] : 0.f;
  }
  __syncthreads();
  #pragma unroll
  for (int i = 0; i < 4; ++i) {
    int pl = tr + i * 8;
    int p = p0 + pl;
    if (p >= P) continue;
    int c = c0 + tp;
    float v = tile[tp][pl];
    if (chw)      v *= chw[c];
    if (rowscale) v *= rowscale[n * P + p];
    int y = p / W, x = p - y * W;
    dst[((size_t)n * nstride + (y + hh) * Wp + (x + hh)) * C + c] = f2bf(v);
  }
}

// ---------------- weight repack ------------------------------------------------------
struct WSeg { const float* src; short* dst; int Ci; int S; int elems; };
struct WPrep { WSeg seg[20]; };

__global__ __launch_bounds__(256) void wprep_kernel(WPrep p, int total) {
  int i = blockIdx.x * 256 + threadIdx.x;
  if (i >= total) return;
  int local = i;
  int si = 0;
  while (local >= p.seg[si].elems) { local -= p.seg[si].elems; ++si; }
  WSeg sg = p.seg[si];
  int ci = local % sg.Ci;
  int q  = local / sg.Ci;
  int s  = q % sg.S;
  int co = q / sg.S;
  float v = sg.src[((size_t)co * sg.Ci + ci) * sg.S + s];
  sg.dst[local] = f2bf(v);
}

// ---------------- conv params --------------------------------------------------------
struct ConvP {
  const short* in;   // bf16 padded NHWC [16][iHp][iWp][Ci]
  const short* w;    // bf16 [Co][S][Ci]
  const float* b1;   // bias (extra) / cls bias (head)
  const float* b2;   // box bias (head)
  short* out_bf;     // extra: padded bf16 NHWC out
  float* out_f;      // head: packed d_out
  int M, Ci, iHp, iWp, Ho, Wo, Co;
  int S, kdim, stride, ioff;
  int oWp, onstride, oh;
  int mbox, row_base;
};

// ---------------- 2-phase double-buffered implicit-GEMM core -------------------------
template<int BM, int BN, bool HEAD>
__device__ __forceinline__ void conv_core(const ConvP p, int bx, int by) {
  constexpr int NA = BM / 64, NB = BN / 64, AM = BM / 32, AN = BN / 32;
  __shared__ short As[2 * BM * 32];
  __shared__ short Bs[2 * BN * 32];
  const int t = threadIdx.x, lane = t & 63, wave = t >> 6;
  const int HW = p.Ho * p.Wo;
  const int sr = t >> 2, slot = (t & 3) * 8;
  const short* aBase[NA];
  const short* bBase[NB];
  #pragma unroll
  for (int i = 0; i < NA; ++i) {
    int pos = bx * BM + sr + i * 64; if (pos >= p.M) pos = p.M - 1;
    int n = pos / HW, rem = pos - n * HW;
    int yo = rem / p.Wo, xo = rem - yo * p.Wo;
    aBase[i] = p.in + ((size_t)(n * p.iHp + yo * p.stride + p.ioff) * p.iWp
                      + xo * p.stride + p.ioff) * p.Ci + slot;
  }
  #pragma unroll
  for (int i = 0; i < NB; ++i) {
    int co = by * BN + sr + i * 64; if (co >= p.Co) co = p.Co - 1;
    bBase[i] = p.w + (size_t)co * p.S * p.Ci + slot;
  }
  const int cs = p.Ci >> 5;          // 32-ci chunks per tap
  const int total = p.S * cs;

  auto stage = [&](int buf, int aoff, int boff) {
    #pragma unroll
    for (int i = 0; i < NA; ++i)
      gload16(aBase[i] + aoff, &As[buf * (BM * 32) + i * 2048 + t * 8]);
    #pragma unroll
    for (int i = 0; i < NB; ++i)
      gload16(bBase[i] + boff, &Bs[buf * (BN * 32) + i * 2048 + t * 8]);
  };

  int ntap = 0, ncc = 0;
  auto aoff_cur = [&]() -> int {
    if (p.S == 1) return ncc * 32;
    unsigned dy = (unsigned)ntap / 3u;
    int dx = ntap - (int)dy * 3;
    return ((int)dy * p.iWp + dx) * p.Ci + ncc * 32;
  };

  stage(0, aoff_cur(), 0);
  ++ncc; if (ncc == cs) { ncc = 0; ++ntap; }
  __syncthreads();                       // tile 0 landed

  f32x4 acc[AM][AN];
  #pragma unroll
  for (int i = 0; i < AM; ++i)
    #pragma unroll
    for (int j = 0; j < AN; ++j)
      acc[i][j] = (f32x4){0.f, 0.f, 0.f, 0.f};

  const int wr = (wave >> 1) * (BM / 2), wc = (wave & 1) * (BN / 2);
  const int lrow = lane & 15, lk = (lane >> 4) * 8;

  int cur = 0;
  for (int ks = 0; ks < total; ++ks) {
    if (ks + 1 < total) {                // issue next tile's loads FIRST (overlap)
      stage(cur ^ 1, aoff_cur(), (ks + 1) * 32);
      ++ncc; if (ncc == cs) { ncc = 0; ++ntap; }
    }
    const short* aRd = &As[cur * (BM * 32) + (wr + lrow) * 32 + lk];
    const short* bRd = &Bs[cur * (BN * 32) + (wc + lrow) * 32 + lk];
    short8 a[AM], b[AN];
    #pragma unroll
    for (int i = 0; i < AM; ++i) a[i] = *reinterpret_cast<const short8*>(aRd + i * 512);
    #pragma unroll
    for (int j = 0; j < AN; ++j) b[j] = *reinterpret_cast<const short8*>(bRd + j * 512);
    #pragma unroll
    for (int i = 0; i < AM; ++i)
      #pragma unroll
      for (int j = 0; j < AN; ++j)
        acc[i][j] = __builtin_amdgcn_mfma_f32_16x16x32_bf16(a[i], b[j], acc[i][j], 0, 0, 0);
    __syncthreads();                     // drains vmcnt(0): next tile ready; reads of cur done
    cur ^= 1;
  }

  const int mk = p.mbox * 81;
  const int rb_ = (lane >> 4) * 4, cl_ = lane & 15;
  #pragma unroll
  for (int i = 0; i < AM; ++i)
    #pragma unroll
    for (int j = 0; j < AN; ++j)
      #pragma unroll
      for (int q = 0; q < 4; ++q) {
        int po = bx * BM + wr + i * 16 + rb_ + q;
        int co = by * BN + wc + j * 16 + cl_;
        if (po >= p.M || co >= p.Co) continue;
        float v = acc[i][j][q];
        if (!HEAD) {
          int n2 = po / HW, sp = po - n2 * HW;
          int y = sp / p.Wo, x = sp - y * p.Wo;
          float v2 = fmaxf(v + p.b1[co], 0.f);
          p.out_bf[((size_t)n2 * p.onstride + (y + p.oh) * p.oWp + (x + p.oh)) * p.Co + co] = f2bf(v2);
        } else {
          int n2 = po / HW, sp = po - n2 * HW;
          int mi, col; float bias;
          if (co < mk) { mi = co / 81; col = co - mi * 81; bias = p.b1[co]; }
          else { int cbx = co - mk; mi = cbx >> 2; col = 81 + (cbx & 3); bias = p.b2[cbx]; }
          size_t orow = (size_t)n2 * 8732 + p.row_base + (size_t)sp * p.mbox + mi;
          p.out_f[orow * 85 + col] = v + bias;
        }
      }
}

__global__ __launch_bounds__(256) void conv_tile64(ConvP p) {
  conv_core<64, 64, false>(p, blockIdx.x, blockIdx.y);
}

// ---------------- grouped head kernel (all 6 heads, one launch) ----------------------
struct HeadPack { ConvP L[6]; int blk0[6]; int nbx[6]; };

__global__ __launch_bounds__(256) void head_grouped(HeadPack h) {
  int bid = blockIdx.x;
  int li = 0;
  #pragma unroll
  for (int i = 1; i < 6; ++i) if (bid >= h.blk0[i]) li = i;
  int local = bid - h.blk0[li];
  int bx = local % h.nbx[li];
  int by = local / h.nbx[li];
  conv_core<128, 128, true>(h.L[li], bx, by);
}

extern "C" void kernel_launch(void* const* d_in, const int* in_sizes, int n_in,
                              void* d_out, int out_size, void* d_ws, size_t ws_size,
                              hipStream_t stream) {
  const float* feat0 = (const float*)d_in[0];
  const float* feat1 = (const float*)d_in[1];
  const float* l2w   = (const float*)d_in[2];
  const float* ew[8]; const float* eb[8];
  for (int i = 0; i < 8; ++i) { ew[i] = (const float*)d_in[3 + 2 * i]; eb[i] = (const float*)d_in[4 + 2 * i]; }
  const float* cw[6]; const float* cb[6]; const float* bw[6]; const float* bb[6];
  for (int i = 0; i < 6; ++i) {
    cw[i] = (const float*)d_in[19 + 4 * i]; cb[i] = (const float*)d_in[20 + 4 * i];
    bw[i] = (const float*)d_in[21 + 4 * i]; bb[i] = (const float*)d_in[22 + 4 * i];
  }
  float* out = (float*)d_out;
  char* ws = (char*)d_ws;
  size_t off = 0;
  auto alloc = [&](size_t bytes) -> char* {
    char* p = ws + off;
    off = (off + bytes + 255) & ~(size_t)255;
    return p;
  };
  float* scale0 = (float*)alloc(23104 * 4);
  char* featStart = ws + off;
  short* f0b = (short*)alloc((size_t)16 * 40 * 40 * 512 * 2);   // 38x38, h=1
  short* f1b = (short*)alloc((size_t)16 * 21 * 21 * 1024 * 2);  // 19x19, h=1
  short* xe0 = (short*)alloc((size_t)16 * 21 * 21 * 256 * 2);   // 19x19, h=1
  short* f2b = (short*)alloc((size_t)16 * 12 * 12 * 512 * 2);   // 10x10, h=1
  short* xe2 = (short*)alloc((size_t)16 * 12 * 12 * 128 * 2);   // 10x10, h=1
  short* f3b = (short*)alloc((size_t)16 * 7 * 7 * 256 * 2);     // 5x5,  h=1
  short* xe4 = (short*)alloc((size_t)16 * 5 * 5 * 128 * 2);     // 5x5,  h=0
  short* f4b = (short*)alloc((size_t)16 * 5 * 5 * 256 * 2);     // 3x3,  h=1
  short* xe6 = (short*)alloc((size_t)16 * 3 * 3 * 128 * 2);     // 3x3,  h=0
  short* f5b = (short*)alloc((size_t)16 * 3 * 3 * 256 * 2);     // 1x1,  h=1
  size_t featBytes = (size_t)((ws + off) - featStart);

  static const int eCo[8] = {256, 512, 128, 256, 128, 256, 128, 256};
  static const int eCi[8] = {1024, 256, 512, 128, 256, 128, 256, 128};
  static const int eS[8]  = {1, 9, 1, 9, 1, 9, 1, 9};
  static const int mbox[6] = {4, 6, 6, 6, 4, 4};
  static const int hCi[6] = {512, 1024, 512, 256, 256, 256};

  WPrep wp; int total = 0; int segi = 0;
  short* ewb[8]; short* hwb[6];
  for (int i = 0; i < 8; ++i) {
    int e = eCo[i] * eCi[i] * eS[i];
    ewb[i] = (short*)alloc((size_t)e * 2);
    wp.seg[segi++] = {ew[i], ewb[i], eCi[i], eS[i], e};
    total += e;
  }
  for (int L = 0; L < 6; ++L) {
    int co = mbox[L] * 85;
    int e = co * hCi[L] * 9;
    hwb[L] = (short*)alloc((size_t)e * 2);
    int ecls = mbox[L] * 81 * hCi[L] * 9;
    wp.seg[segi++] = {cw[L], hwb[L], hCi[L], 9, ecls};
    wp.seg[segi++] = {bw[L], hwb[L] + (size_t)mbox[L] * 81 * 9 * hCi[L], hCi[L], 9, e - ecls};
    total += e;
  }

  hipMemsetAsync(featStart, 0, featBytes, stream);
  l2norm_kernel<<<dim3((23104 + 63) / 64), 256, 0, stream>>>(feat0, scale0, 512, 1444, 23104);
  to_nhwc_kernel<<<dim3(46, 16, 16), 256, 0, stream>>>(feat0, f0b, scale0, l2w, 512, 38, 38, 40, 1600, 1);
  to_nhwc_kernel<<<dim3(12, 32, 16), 256, 0, stream>>>(feat1, f1b, nullptr, nullptr, 1024, 19, 19, 21, 441, 1);
  wprep_kernel<<<dim3((total + 255) / 256), 256, 0, stream>>>(wp, total);

  auto mkP = [&](const short* in, const short* wbuf, const float* b1, const float* b2,
                 short* outb, float* outf, int Ci, int iHp, int iWp, int Ho, int Wo,
                 int Co, int S, int kd, int st, int ioff, int oWp, int onstride, int oh,
                 int m, int rb) {
    ConvP p{}; p.in = in; p.w = wbuf; p.b1 = b1; p.b2 = b2; p.out_bf = outb; p.out_f = outf;
    p.M = 16 * Ho * Wo; p.Ci = Ci; p.iHp = iHp; p.iWp = iWp; p.Ho = Ho; p.Wo = Wo; p.Co = Co;
    p.S = S; p.kdim = kd; p.stride = st; p.ioff = ioff;
    p.oWp = oWp; p.onstride = onstride; p.oh = oh; p.mbox = m; p.row_base = rb;
    return p;
  };
  auto run64 = [&](ConvP p) {
    conv_tile64<<<dim3((p.M + 63) / 64, (p.Co + 63) / 64), 256, 0, stream>>>(p);
  };

  // extras chain (2-phase pipelined 64x64)
  run64(mkP(f1b, ewb[0], eb[0], nullptr, xe0, nullptr, 1024, 21, 21, 19, 19, 256, 1, 1, 1, 1, 21, 441, 1, 0, 0));
  run64(mkP(xe0, ewb[1], eb[1], nullptr, f2b, nullptr,  256, 21, 21, 10, 10, 512, 9, 3, 2, 0, 12, 144, 1, 0, 0));
  run64(mkP(f2b, ewb[2], eb[2], nullptr, xe2, nullptr,  512, 12, 12, 10, 10, 128, 1, 1, 1, 1, 12, 144, 1, 0, 0));
  run64(mkP(xe2, ewb[3], eb[3], nullptr, f3b, nullptr,  128, 12, 12,  5,  5, 256, 9, 3, 2, 0,  7,  49, 1, 0, 0));
  run64(mkP(f3b, ewb[4], eb[4], nullptr, xe4, nullptr,  256,  7,  7,  5,  5, 128, 1, 1, 1, 1,  5,  25, 0, 0, 0));
  run64(mkP(xe4, ewb[5], eb[5], nullptr, f4b, nullptr,  128,  5,  5,  3,  3, 256, 9, 3, 1, 0,  5,  25, 1, 0, 0));
  run64(mkP(f4b, ewb[6], eb[6], nullptr, xe6, nullptr,  256,  5,  5,  3,  3, 128, 1, 1, 1, 1,  3,   9, 0, 0, 0));
  run64(mkP(xe6, ewb[7], eb[7], nullptr, f5b, nullptr,  128,  3,  3,  1,  1, 256, 9, 3, 1, 0,  3,   9, 1, 0, 0));

  // all 6 heads in ONE launch; longest-K layer (head1) first for tail balance
  HeadPack h;
  h.L[0] = mkP(f1b, hwb[1], cb[1], bb[1], nullptr, out, 1024, 21, 21, 19, 19, 6 * 85, 9, 3, 1, 0, 0, 0, 0, 6, 5776);
  h.L[1] = mkP(f0b, hwb[0], cb[0], bb[0], nullptr, out,  512, 40, 40, 38, 38, 4 * 85, 9, 3, 1, 0, 0, 0, 0, 4, 0);
  h.L[2] = mkP(f2b, hwb[2], cb[2], bb[2], nullptr, out,  512, 12, 12, 10, 10, 6 * 85, 9, 3, 1, 0, 0, 0, 0, 6, 7942);
  h.L[3] = mkP(f3b, hwb[3], cb[3], bb[3], nullptr, out,  256,  7,  7,  5,  5, 6 * 85, 9, 3, 1, 0, 0, 0, 0, 6, 8542);
  h.L[4] = mkP(f4b, hwb[4], cb[4], bb[4], nullptr, out,  256,  5,  5,  3,  3, 4 * 85, 9, 3, 1, 0, 0, 0, 0, 4, 8692);
  h.L[5] = mkP(f5b, hwb[5], cb[5], bb[5], nullptr, out,  256,  3,  3,  1,  1, 4 * 85, 9, 3, 1, 0, 0, 0, 0, 4, 8728);
  int nblk = 0;
  for (int i = 0; i < 6; ++i) {
    h.blk0[i] = nblk;
    h.nbx[i] = (h.L[i].M + 127) / 128;
    int nby = (h.L[i].Co + 127) / 128;
    nblk += h.nbx[i] * nby;
  }
  head_grouped<<<dim3(nblk), 256, 0, stream>>>(h);
}